// Round 7
// baseline (1479.931 us; speedup 1.0000x reference)
//
#include <hip/hip_runtime.h>
#include <hip/hip_bf16.h>
#include <math.h>

#define BB 64
#define TT 128
#define MM 256
#define DD 256
#define NB 4

// lgkm-only barrier: cross-thread deps are all through LDS. Avoids the
// vmcnt(0) drain of __syncthreads (ring global writes are thread-column-
// exclusive and never need barrier visibility).
#define BARL()                                          \
  do {                                                  \
    asm volatile("s_waitcnt lgkmcnt(0)" ::: "memory");  \
    __builtin_amdgcn_s_barrier();                       \
  } while (0)

// One block per batch element; 1024 threads = 16 waves (4 waves/EU exactly).
// waves_per_eu(4,4) unlocks the 128-VGPR budget so proc_W stays register-resident.
__global__ __launch_bounds__(1024) __attribute__((amdgpu_waves_per_eu(4, 4)))
void swarm_kernel(const float* __restrict__ x,        // [B,T,8]
                  const float* __restrict__ in_W,     // [D,8]
                  const float* __restrict__ in_b,     // [D]
                  const float* __restrict__ out_W,    // [8,D]
                  const float* __restrict__ out_b,    // [8]
                  const float* __restrict__ proc_W,   // [1,D,D]
                  const float* __restrict__ proc_b,   // [1,D]
                  const float* __restrict__ dest,     // [N,M]
                  const float* __restrict__ jg_W,     // [N,1,D]
                  const float* __restrict__ jg_b,     // [N,1]
                  const float* __restrict__ ctx_strength, // [N]
                  const float* __restrict__ phase,    // [N,16]
                  const float* __restrict__ ptr_init, // [N,B]
                  float* __restrict__ out,            // [B,T,8]
                  float* __restrict__ ws)             // ring: B*M*D floats
{
  const int b    = blockIdx.x;
  const int tid  = threadIdx.x;
  const int wave = tid >> 6;
  const int lane = tid & 63;
  const int c    = tid >> 8;     // 0..3  (k-quarter)
  const int jj   = tid & 255;    // 0..255 (output row)
  const bool j256 = (tid < 256);
  const int j = tid;             // valid row index when j256

  float* __restrict__ ring = ws + (size_t)b * (MM * DD);

  __shared__ __align__(16) float s_lds[DD];
  __shared__ float part_lds[4 * DD];
  __shared__ float hid_lds[NB * DD];
  __shared__ float red_lds[8];         // 2 slots (being parity) x 4 waves
  __shared__ float red2_lds[32];
  __shared__ float ptr_lds[NB];
  // per-row constants kept in LDS (register diet)
  __shared__ float cst_inWT[8 * DD];   // in_W transposed: [cc][j]
  __shared__ float cst_inb[DD];
  __shared__ float cst_pb[DD];
  __shared__ float cst_jgW[NB * DD];
  __shared__ float cst_ph[NB * DD];    // 0.1*phase padded to D
  __shared__ float cst_outW[8 * DD];   // out_W [o][j]
  __shared__ float cst_sig[NB];
  __shared__ float cst_jgb[NB];

  // ---- distribute proc_W into registers: Wreg[kk] = W[jj][c*64+kk] ----
  float Wreg[64];
  {
    const float4* src = (const float4*)(proc_W + (size_t)jj * DD + c * 64);
    #pragma unroll
    for (int q = 0; q < 16; ++q) {
      float4 v = src[q];
      Wreg[4*q+0] = v.x; Wreg[4*q+1] = v.y; Wreg[4*q+2] = v.z; Wreg[4*q+3] = v.w;
    }
  }
  // pin into VGPRs: opaque defs prevent rematerialization-from-global
  #pragma unroll
  for (int q = 0; q < 64; ++q) asm volatile("" : "+v"(Wreg[q]));

  // ---- load constants into LDS ----
  for (int i = tid; i < 8 * DD; i += 1024) {
    int cc = i >> 8, jx = i & 255;
    cst_inWT[i] = in_W[jx * 8 + cc];      // transpose
    cst_outW[i] = out_W[i];
  }
  {
    int i = tid;                           // NB*DD == 1024 exactly
    int n = i >> 8, jx = i & 255;
    cst_jgW[i] = jg_W[i];
    cst_ph[i]  = (jx < 16) ? 0.1f * phase[n * 16 + jx] : 0.f;
    hid_lds[i] = 0.f;
  }
  if (j256) { cst_inb[j] = in_b[j]; cst_pb[j] = proc_b[j]; }
  if (tid < NB) {
    cst_sig[tid] = 1.f / (1.f + expf(-ctx_strength[tid]));
    cst_jgb[tid] = jg_b[tid];
    ptr_lds[tid] = ptr_init[tid * BB + b];
  }

  // ---- zero ring (ws is poisoned 0xAA before every launch) ----
  {
    float4 z4 = make_float4(0.f, 0.f, 0.f, 0.f);
    float4* r4 = (float4*)ring;
    #pragma unroll
    for (int q = 0; q < (MM * DD / 4) / 1024; ++q)
      r4[q * 1024 + tid] = z4;
  }
  __syncthreads();   // full barrier: cross-thread global-write visibility (init only)

  float prevp = 0.f, dst_prev = 0.f, dst_cur = 0.f;

  for (int t = 0; t < TT; ++t) {
    float inp_r = 0.f;
    if (j256) {
      const float* xt = x + ((size_t)b * TT + t) * 8;
      float a = cst_inb[j];
      #pragma unroll
      for (int cc = 0; cc < 8; ++cc) a = fmaf(xt[cc], cst_inWT[cc * DD + j], a);
      inp_r = a;
    }
    float sacc = 0.f;

    #pragma unroll
    for (int n = 0; n < NB; ++n) {
      float p = 0.f, w5[5];
      int basei = 0;

      // ---- phase A (waves 0-3): weights, ring gather, pre-activation ----
      if (j256) {
        p = ptr_lds[n];
        basei = (int)floorf(p);
        if (basei < 0) basei = 0;
        if (basei > MM - 1) basei = MM - 1;
        if (tid == 0) dst_cur = dest[n * MM + basei];   // prefetch for deferred D
        float v5[5], mx = -1e30f;
        #pragma unroll
        for (int i = 0; i < 5; ++i) {
          int idx = (basei + i - 2 + MM) & (MM - 1);
          float d = (float)idx - p + 128.f;
          d -= 256.f * floorf(d * (1.f / 256.f));   // jnp.mod(d,256)
          float del = d - 128.f;
          v5[i] = -(del * del) * 0.125f;            // -(delta^2)/TEMP
          mx = fmaxf(mx, v5[i]);
        }
        float se = 0.f;
        #pragma unroll
        for (int i = 0; i < 5; ++i) { w5[i] = expf(v5[i] - mx); se += w5[i]; }
        float inv = 1.f / se;
        float ctx = 0.f;
        #pragma unroll
        for (int i = 0; i < 5; ++i) {
          w5[i] *= inv;
          int idx = (basei + i - 2 + MM) & (MM - 1);
          ctx = fmaf(w5[i], ring[idx * DD + j], ctx);
        }
        float comb = inp_r + cst_sig[n] * ctx + cst_ph[n * DD + j];
        s_lds[j] = tanhf(comb + hid_lds[n * DD + j]);
      }
      BARL();   // bar1: s_lds ready

      // ---- deferred phase D for being n-1 (tid 0 only) ----
      if (n > 0 && tid == 0) {
        int slot = (n - 1) & 1;
        float jl = ((red_lds[slot * 4 + 0] + red_lds[slot * 4 + 1]) +
                    (red_lds[slot * 4 + 2] + red_lds[slot * 4 + 3])) + cst_jgb[n - 1];
        float walk = prevp + 1.f;
        if (walk >= 256.f) walk -= 256.f;
        ptr_lds[n - 1] = (jl > 0.f) ? dst_prev : walk;  // hard gate: pr>0.5 <=> jl>0
      }

      // ---- phase B (all 16 waves): matvec partials, W register-resident ----
      // Chunked 4x4: caps in-flight ds_read_b128 results at 4 float4s (16 VGPRs)
      // so peak pressure stays under the 128-VGPR budget (no Wreg spill).
      {
        float a0 = 0.f, a1 = 0.f, a2 = 0.f, a3 = 0.f;
        const float4* s4 = (const float4*)(s_lds + (c << 6));
        #pragma unroll
        for (int g = 0; g < 4; ++g) {
          float4 sv0 = s4[4*g+0], sv1 = s4[4*g+1], sv2 = s4[4*g+2], sv3 = s4[4*g+3];
          a0 = fmaf(Wreg[16*g+ 0], sv0.x, a0);
          a1 = fmaf(Wreg[16*g+ 1], sv0.y, a1);
          a2 = fmaf(Wreg[16*g+ 2], sv0.z, a2);
          a3 = fmaf(Wreg[16*g+ 3], sv0.w, a3);
          a0 = fmaf(Wreg[16*g+ 4], sv1.x, a0);
          a1 = fmaf(Wreg[16*g+ 5], sv1.y, a1);
          a2 = fmaf(Wreg[16*g+ 6], sv1.z, a2);
          a3 = fmaf(Wreg[16*g+ 7], sv1.w, a3);
          a0 = fmaf(Wreg[16*g+ 8], sv2.x, a0);
          a1 = fmaf(Wreg[16*g+ 9], sv2.y, a1);
          a2 = fmaf(Wreg[16*g+10], sv2.z, a2);
          a3 = fmaf(Wreg[16*g+11], sv2.w, a3);
          a0 = fmaf(Wreg[16*g+12], sv3.x, a0);
          a1 = fmaf(Wreg[16*g+13], sv3.y, a1);
          a2 = fmaf(Wreg[16*g+14], sv3.z, a2);
          a3 = fmaf(Wreg[16*g+15], sv3.w, a3);
        }
        part_lds[(c << 8) + jj] = (a0 + a1) + (a2 + a3);
      }
      BARL();   // bar2: partials ready

      // ---- phase C (waves 0-3): combine, s2, ring RMW, gate partials ----
      if (j256) {
        float sum = ((part_lds[j] + part_lds[DD + j]) +
                     (part_lds[2 * DD + j] + part_lds[3 * DD + j])) + cst_pb[j];
        float s2 = tanhf(sum);
        hid_lds[n * DD + j] = s2;
        sacc += s2;
        // ring column j is thread-exclusive: re-read (L1-hot), RMW, no drain
        #pragma unroll
        for (int i = 0; i < 5; ++i) {
          int idx = (basei + i - 2 + MM) & (MM - 1);
          float* rp = ring + idx * DD + j;
          *rp = *rp + w5[i] * s2;
        }
        float v = s2 * cst_jgW[n * DD + j];
        #pragma unroll
        for (int off = 32; off > 0; off >>= 1) v += __shfl_down(v, off, 64);
        if (lane == 0) red_lds[(n & 1) * 4 + wave] = v;
      }
      // carry p / dest prefetch for the deferred D
      prevp = p; dst_prev = dst_cur;
      // no barrier here: next A's s_lds write only conflicts with B readers (bar2'd)
    } // beings

    // ---- output: combined[o] = out_b[o] + 0.25 * sum_j sacc[j]*out_W[o][j] ----
    if (j256) {
      #pragma unroll
      for (int o = 0; o < 8; ++o) {
        float v = sacc * cst_outW[o * DD + j];
        #pragma unroll
        for (int off = 32; off > 0; off >>= 1) v += __shfl_down(v, off, 64);
        if (lane == 0) red2_lds[o * 4 + wave] = v;
      }
    }
    BARL();   // red2 + red_lds(being 3) ready

    // deferred D for being 3 (tid 0)
    if (tid == 0) {
      float jl = ((red_lds[4] + red_lds[5]) + (red_lds[6] + red_lds[7])) + cst_jgb[3];
      float walk = prevp + 1.f;
      if (walk >= 256.f) walk -= 256.f;
      ptr_lds[3] = (jl > 0.f) ? dst_prev : walk;
    }
    if (tid < 8) {
      float s = (red2_lds[tid * 4 + 0] + red2_lds[tid * 4 + 1]) +
                (red2_lds[tid * 4 + 2] + red2_lds[tid * 4 + 3]);
      out[((size_t)b * TT + t) * 8 + tid] = out_b[tid] + 0.25f * s;
    }
    // no trailing barrier: only tids 0-7 read red2/red, and they do so before
    // their own next-t work; next writers of red/red2 are many barriers away
  } // t
}

extern "C" void kernel_launch(void* const* d_in, const int* in_sizes, int n_in,
                              void* d_out, int out_size, void* d_ws, size_t ws_size,
                              hipStream_t stream) {
  const float* x        = (const float*)d_in[0];
  const float* in_W     = (const float*)d_in[1];
  const float* in_b     = (const float*)d_in[2];
  const float* out_W    = (const float*)d_in[3];
  const float* out_b    = (const float*)d_in[4];
  const float* proc_W   = (const float*)d_in[5];
  const float* proc_b   = (const float*)d_in[6];
  const float* dest     = (const float*)d_in[7];
  const float* jg_W     = (const float*)d_in[8];
  const float* jg_b     = (const float*)d_in[9];
  const float* ctx_s    = (const float*)d_in[10];
  const float* phase    = (const float*)d_in[11];
  const float* ptr_init = (const float*)d_in[12];
  float* outp = (float*)d_out;
  float* ws   = (float*)d_ws;

  hipLaunchKernelGGL(swarm_kernel, dim3(BB), dim3(1024), 0, stream,
                     x, in_W, in_b, out_W, out_b, proc_W, proc_b, dest,
                     jg_W, jg_b, ctx_s, phase, ptr_init, outp, ws);
}

// Round 9
// 1447.427 us; speedup vs baseline: 1.0225x; 1.0225x over previous
//
#include <hip/hip_runtime.h>
#include <hip/hip_bf16.h>
#include <math.h>

#define BB 64
#define TT 128
#define MM 256
#define DD 256
#define NB 4
#define THREADS 512

// lgkm-only barrier: cross-thread deps are all through LDS. Avoids the
// vmcnt(0) drain of __syncthreads (ring global writes are thread-column-
// exclusive and never need barrier visibility).
#define BARL()                                          \
  do {                                                  \
    asm volatile("s_waitcnt lgkmcnt(0)" ::: "memory");  \
    __builtin_amdgcn_s_barrier();                       \
  } while (0)

// One block per batch element; 512 threads = 8 waves = 2 waves/EU.
// __launch_bounds__(512, 2): min 2 waves/EU -> VGPR budget 256.
// The LDS pad (>80KB total) forces 1 block/CU so the occupancy heuristic
// cannot target more than 2 waves/EU. Requirement ~175 VGPRs << 256:
// Wreg[128] (half a proc_W row per thread) stays register-resident with
// huge headroom -- no spill, no remat.
__global__ __launch_bounds__(THREADS, 2)
void swarm_kernel(const float* __restrict__ x,        // [B,T,8]
                  const float* __restrict__ in_W,     // [D,8]
                  const float* __restrict__ in_b,     // [D]
                  const float* __restrict__ out_W,    // [8,D]
                  const float* __restrict__ out_b,    // [8]
                  const float* __restrict__ proc_W,   // [1,D,D]
                  const float* __restrict__ proc_b,   // [1,D]
                  const float* __restrict__ dest,     // [N,M]
                  const float* __restrict__ jg_W,     // [N,1,D]
                  const float* __restrict__ jg_b,     // [N,1]
                  const float* __restrict__ ctx_strength, // [N]
                  const float* __restrict__ phase,    // [N,16]
                  const float* __restrict__ ptr_init, // [N,B]
                  float* __restrict__ out,            // [B,T,8]
                  float* __restrict__ ws)             // ring: B*M*D floats
{
  const int b    = blockIdx.x;
  const int tid  = threadIdx.x;
  const int wave = tid >> 6;
  const int lane = tid & 63;
  const int c    = tid >> 8;     // 0..1  (k-half)
  const int jj   = tid & 255;    // 0..255 (output row)
  const bool j256 = (tid < 256);
  const int j = tid;             // valid row index when j256

  float* __restrict__ ring = ws + (size_t)b * (MM * DD);

  __shared__ __align__(16) float s_lds[DD];
  __shared__ float part_lds[2 * DD];   // 2 k-halves
  __shared__ float hid_lds[NB * DD];
  __shared__ float red_lds[8];         // 2 slots (being parity) x 4 waves
  __shared__ float red2_lds[32];
  __shared__ float ptr_lds[NB];
  // per-row constants kept in LDS (register diet)
  __shared__ float cst_inWT[8 * DD];   // in_W transposed: [cc][j]
  __shared__ float cst_inb[DD];
  __shared__ float cst_pb[DD];
  __shared__ float cst_jgW[NB * DD];
  __shared__ float cst_ph[NB * DD];    // 0.1*phase padded to D
  __shared__ float cst_outW[8 * DD];   // out_W [o][j]
  __shared__ float cst_sig[NB];
  __shared__ float cst_jgb[NB];
  // occupancy pad: pushes LDS past 80KB so only 1 block/CU fits ->
  // occupancy target 8 waves/CU = 2 waves/EU -> VGPR budget 256.
  // Free at runtime: grid=64 on 256 CUs never co-schedules 2 blocks anyway.
  __shared__ float pad_lds[13312];     // 52 KB

  // ---- distribute proc_W into registers: Wreg[kk] = W[jj][c*128+kk] ----
  float Wreg[128];
  {
    const float4* src = (const float4*)(proc_W + (size_t)jj * DD + (c << 7));
    #pragma unroll
    for (int q = 0; q < 32; ++q) {
      float4 v = src[q];
      Wreg[4*q+0] = v.x; Wreg[4*q+1] = v.y; Wreg[4*q+2] = v.z; Wreg[4*q+3] = v.w;
    }
  }
  #pragma unroll
  for (int q = 0; q < 128; ++q) asm volatile("" : "+v"(Wreg[q]));

  // keep the pad allocated (store can't be DSE'd past the asm memory clobbers)
  pad_lds[tid] = 0.f;

  // ---- load constants into LDS ----
  for (int i = tid; i < 8 * DD; i += THREADS) {
    int cc = i >> 8, jx = i & 255;
    cst_inWT[i] = in_W[jx * 8 + cc];      // transpose
    cst_outW[i] = out_W[i];
  }
  for (int i = tid; i < NB * DD; i += THREADS) {
    int n = i >> 8, jx = i & 255;
    cst_jgW[i] = jg_W[i];
    cst_ph[i]  = (jx < 16) ? 0.1f * phase[n * 16 + jx] : 0.f;
    hid_lds[i] = 0.f;
  }
  if (j256) { cst_inb[j] = in_b[j]; cst_pb[j] = proc_b[j]; }
  if (tid < NB) {
    cst_sig[tid] = 1.f / (1.f + expf(-ctx_strength[tid]));
    cst_jgb[tid] = jg_b[tid];
    ptr_lds[tid] = ptr_init[tid * BB + b];
  }

  // ---- zero ring (ws is poisoned 0xAA before every launch) ----
  {
    float4 z4 = make_float4(0.f, 0.f, 0.f, 0.f);
    float4* r4 = (float4*)ring;
    #pragma unroll
    for (int q = 0; q < (MM * DD / 4) / THREADS; ++q)
      r4[q * THREADS + tid] = z4;
  }
  __syncthreads();   // full barrier: cross-thread global-write visibility (init only)

  float prevp = 0.f, dst_prev = 0.f, dst_cur = 0.f;

  for (int t = 0; t < TT; ++t) {
    float inp_r = 0.f;
    if (j256) {
      const float* xt = x + ((size_t)b * TT + t) * 8;
      float a = cst_inb[j];
      #pragma unroll
      for (int cc = 0; cc < 8; ++cc) a = fmaf(xt[cc], cst_inWT[cc * DD + j], a);
      inp_r = a;
    }
    float sacc = 0.f;

    #pragma unroll
    for (int n = 0; n < NB; ++n) {
      float p = 0.f, w5[5];
      int basei = 0;

      // ---- phase A (waves 0-3): weights, ring gather, pre-activation ----
      if (j256) {
        p = ptr_lds[n];
        basei = (int)floorf(p);
        if (basei < 0) basei = 0;
        if (basei > MM - 1) basei = MM - 1;
        if (tid == 0) dst_cur = dest[n * MM + basei];   // prefetch for deferred D
        float v5[5], mx = -1e30f;
        #pragma unroll
        for (int i = 0; i < 5; ++i) {
          int idx = (basei + i - 2 + MM) & (MM - 1);
          float d = (float)idx - p + 128.f;
          d -= 256.f * floorf(d * (1.f / 256.f));   // jnp.mod(d,256)
          float del = d - 128.f;
          v5[i] = -(del * del) * 0.125f;            // -(delta^2)/TEMP
          mx = fmaxf(mx, v5[i]);
        }
        float se = 0.f;
        #pragma unroll
        for (int i = 0; i < 5; ++i) { w5[i] = expf(v5[i] - mx); se += w5[i]; }
        float inv = 1.f / se;
        float ctx = 0.f;
        #pragma unroll
        for (int i = 0; i < 5; ++i) {
          w5[i] *= inv;
          int idx = (basei + i - 2 + MM) & (MM - 1);
          ctx = fmaf(w5[i], ring[idx * DD + j], ctx);
        }
        float comb = inp_r + cst_sig[n] * ctx + cst_ph[n * DD + j];
        s_lds[j] = tanhf(comb + hid_lds[n * DD + j]);
      }
      BARL();   // bar1: s_lds ready

      // ---- deferred phase D for being n-1 (tid 0 only) ----
      if (n > 0 && tid == 0) {
        int slot = (n - 1) & 1;
        float jl = ((red_lds[slot * 4 + 0] + red_lds[slot * 4 + 1]) +
                    (red_lds[slot * 4 + 2] + red_lds[slot * 4 + 3])) + cst_jgb[n - 1];
        float walk = prevp + 1.f;
        if (walk >= 256.f) walk -= 256.f;
        ptr_lds[n - 1] = (jl > 0.f) ? dst_prev : walk;  // hard gate: pr>0.5 <=> jl>0
      }

      // ---- phase B (all 8 waves): matvec partials, W register-resident ----
      // Chunked 8x4: caps in-flight ds_read_b128 results at 4 float4s (16 VGPRs).
      {
        float a0 = 0.f, a1 = 0.f, a2 = 0.f, a3 = 0.f;
        const float4* s4 = (const float4*)(s_lds + (c << 7));
        #pragma unroll
        for (int g = 0; g < 8; ++g) {
          float4 sv0 = s4[4*g+0], sv1 = s4[4*g+1], sv2 = s4[4*g+2], sv3 = s4[4*g+3];
          a0 = fmaf(Wreg[16*g+ 0], sv0.x, a0);
          a1 = fmaf(Wreg[16*g+ 1], sv0.y, a1);
          a2 = fmaf(Wreg[16*g+ 2], sv0.z, a2);
          a3 = fmaf(Wreg[16*g+ 3], sv0.w, a3);
          a0 = fmaf(Wreg[16*g+ 4], sv1.x, a0);
          a1 = fmaf(Wreg[16*g+ 5], sv1.y, a1);
          a2 = fmaf(Wreg[16*g+ 6], sv1.z, a2);
          a3 = fmaf(Wreg[16*g+ 7], sv1.w, a3);
          a0 = fmaf(Wreg[16*g+ 8], sv2.x, a0);
          a1 = fmaf(Wreg[16*g+ 9], sv2.y, a1);
          a2 = fmaf(Wreg[16*g+10], sv2.z, a2);
          a3 = fmaf(Wreg[16*g+11], sv2.w, a3);
          a0 = fmaf(Wreg[16*g+12], sv3.x, a0);
          a1 = fmaf(Wreg[16*g+13], sv3.y, a1);
          a2 = fmaf(Wreg[16*g+14], sv3.z, a2);
          a3 = fmaf(Wreg[16*g+15], sv3.w, a3);
        }
        part_lds[(c << 8) + jj] = (a0 + a1) + (a2 + a3);
      }
      BARL();   // bar2: partials ready

      // ---- phase C (waves 0-3): combine, s2, ring RMW, gate partials ----
      if (j256) {
        float sum = (part_lds[j] + part_lds[DD + j]) + cst_pb[j];
        float s2 = tanhf(sum);
        hid_lds[n * DD + j] = s2;
        sacc += s2;
        // ring column j is thread-exclusive: re-read (L1-hot), RMW, no drain
        #pragma unroll
        for (int i = 0; i < 5; ++i) {
          int idx = (basei + i - 2 + MM) & (MM - 1);
          float* rp = ring + idx * DD + j;
          *rp = *rp + w5[i] * s2;
        }
        float v = s2 * cst_jgW[n * DD + j];
        #pragma unroll
        for (int off = 32; off > 0; off >>= 1) v += __shfl_down(v, off, 64);
        if (lane == 0) red_lds[(n & 1) * 4 + wave] = v;
      }
      // carry p / dest prefetch for the deferred D
      prevp = p; dst_prev = dst_cur;
      // no barrier here: next A's s_lds write only conflicts with B readers (bar2'd)
    } // beings

    // ---- output: combined[o] = out_b[o] + 0.25 * sum_j sacc[j]*out_W[o][j] ----
    if (j256) {
      #pragma unroll
      for (int o = 0; o < 8; ++o) {
        float v = sacc * cst_outW[o * DD + j];
        #pragma unroll
        for (int off = 32; off > 0; off >>= 1) v += __shfl_down(v, off, 64);
        if (lane == 0) red2_lds[o * 4 + wave] = v;
      }
    }
    BARL();   // red2 + red_lds(being 3) ready

    // deferred D for being 3 (tid 0)
    if (tid == 0) {
      float jl = ((red_lds[4] + red_lds[5]) + (red_lds[6] + red_lds[7])) + cst_jgb[3];
      float walk = prevp + 1.f;
      if (walk >= 256.f) walk -= 256.f;
      ptr_lds[3] = (jl > 0.f) ? dst_prev : walk;
    }
    if (tid < 8) {
      float s = (red2_lds[tid * 4 + 0] + red2_lds[tid * 4 + 1]) +
                (red2_lds[tid * 4 + 2] + red2_lds[tid * 4 + 3]);
      out[((size_t)b * TT + t) * 8 + tid] = out_b[tid] + 0.25f * s;
    }
    // no trailing barrier: only tids 0-7 read red2/red, and they do so before
    // their own next-t work; next writers of red/red2 are many barriers away
  } // t
}

extern "C" void kernel_launch(void* const* d_in, const int* in_sizes, int n_in,
                              void* d_out, int out_size, void* d_ws, size_t ws_size,
                              hipStream_t stream) {
  const float* x        = (const float*)d_in[0];
  const float* in_W     = (const float*)d_in[1];
  const float* in_b     = (const float*)d_in[2];
  const float* out_W    = (const float*)d_in[3];
  const float* out_b    = (const float*)d_in[4];
  const float* proc_W   = (const float*)d_in[5];
  const float* proc_b   = (const float*)d_in[6];
  const float* dest     = (const float*)d_in[7];
  const float* jg_W     = (const float*)d_in[8];
  const float* jg_b     = (const float*)d_in[9];
  const float* ctx_s    = (const float*)d_in[10];
  const float* phase    = (const float*)d_in[11];
  const float* ptr_init = (const float*)d_in[12];
  float* outp = (float*)d_out;
  float* ws   = (float*)d_ws;

  hipLaunchKernelGGL(swarm_kernel, dim3(BB), dim3(THREADS), 0, stream,
                     x, in_W, in_b, out_W, out_b, proc_W, proc_b, dest,
                     jg_W, jg_b, ctx_s, phase, ptr_init, outp, ws);
}